// Round 15
// baseline (64.784 us; speedup 1.0000x reference)
//
#include <hip/hip_runtime.h>

// UpsampleFlow2: Gaussian Nadaraya-Watson upsampling.
// out [B,3,N] = (sum_s k*f)/(sum_s k), k = exp(-|x-y|^2/r^2).
// exp(-|x|^2/r^2) cancels in num/den ->
//   k' = exp2( fma(px,ax, fma(py,ay, fma(pz,az, bias))) )
//   a = c2*y, bias = cy*|y|^2, c2=2*log2e/r^2, cy=-log2e/r^2.
//
// R15: SINGLE DISPATCH via atomic ticket (not grid.sync -- R10's coop spin
// cost 115us). R14 closed the VALU book: scalar/pk/poly inner all ~31us at
// minimal traffic. Remaining untested structure: the 2-dispatch graph tax.
// Phase-1 = R8 verbatim (PPT=8, CHUNK=128, SC=16, 256 blocks, bounds(256,2)).
// Then: threadfence; tid0 atomicAdd(&cnt[nb]); last block (old==SC-1)
// combines its nb's 16 partials (L2-hot) + normalizes + writes out.
// cnt zeroed by 64B hipMemsetAsync at capture (graph-legal; replays rerun
// it) -- robust against the 0xAA ws poison. Combine math is order-fixed ->
// deterministic output regardless of which block wins the ticket.

constexpr int B_ = 4, N_ = 8192, S_ = 2048;
constexpr int BLOCK = 256, PPT = 8, SC = 16;
constexpr int PTS_PER_BLOCK = BLOCK * PPT;      // 2048
constexpr int NBPB = N_ / PTS_PER_BLOCK;        // 4
constexpr int NB = B_ * NBPB;                   // 16
constexpr int CHUNK = S_ / SC;                  // 128
constexpr int BN = B_ * N_;                     // 32768
constexpr float LOG2E = 1.4426950408889634f;

__global__ __launch_bounds__(BLOCK, 2) void uf2_one(
    const float* __restrict__ xyz,
    const float* __restrict__ sxyz,
    const float* __restrict__ sflow,
    const int* __restrict__ resol,
    float4* __restrict__ part,
    int* __restrict__ cnt,
    float* __restrict__ out)
{
    __shared__ float4 As[CHUNK];   // (c2*yx, c2*yy, c2*yz, cy*|y|^2)
    __shared__ float4 Fs[CHUNK];   // (fx, fy, fz, unused)

    const int nb = blockIdx.x % NB;
    const int sc = blockIdx.x / NB;
    const int b  = nb / NBPB;
    const int n0 = (nb % NBPB) * PTS_PER_BLOCK;
    const int s0 = sc * CHUNK;

    const float r = (float)resol[0];            // INITIAL_RADIUS(=1)*resol
    const float inv_r2 = 1.0f / (r * r);
    const float c2 = 2.0f * inv_r2 * LOG2E;
    const float cy = -inv_r2 * LOG2E;

    // ---- stage + pack sparse chunk into LDS ----
    const float* yb = sxyz  + b * 3 * S_;
    const float* fb = sflow + b * 3 * S_;
    for (int t = threadIdx.x; t < CHUNK; t += BLOCK) {
        const int s = s0 + t;
        const float yx = yb[s], yy = yb[S_ + s], yz = yb[2 * S_ + s];
        const float fx = fb[s], fy = fb[S_ + s], fz = fb[2 * S_ + s];
        As[t] = make_float4(c2 * yx, c2 * yy, c2 * yz,
                            cy * (yx * yx + yy * yy + yz * yz));
        Fs[t] = make_float4(fx, fy, fz, 0.0f);
    }
    __syncthreads();

    // ---- per-thread query points ----
    const float* xb = xyz + b * 3 * N_;
    float px[PPT], py[PPT], pz[PPT];
    float ax[PPT], ay[PPT], az[PPT], aw[PPT];
#pragma unroll
    for (int p = 0; p < PPT; ++p) {
        const int n = n0 + threadIdx.x + p * BLOCK;
        px[p] = xb[n]; py[p] = xb[N_ + n]; pz[p] = xb[2 * N_ + n];
        ax[p] = 0.f; ay[p] = 0.f; az[p] = 0.f; aw[p] = 0.f;
    }

    // ---- main loop (R5/R8-proven codegen) ----
#pragma unroll 2
    for (int t = 0; t < CHUNK; ++t) {
        const float4 a = As[t];   // broadcast ds_read_b128
        const float4 f = Fs[t];
#pragma unroll
        for (int p = 0; p < PPT; ++p) {
            float e = fmaf(pz[p], a.z, a.w);
            e = fmaf(py[p], a.y, e);
            e = fmaf(px[p], a.x, e);
            const float k = __builtin_amdgcn_exp2f(e);
            ax[p] = fmaf(k, f.x, ax[p]);
            ay[p] = fmaf(k, f.y, ay[p]);
            az[p] = fmaf(k, f.z, az[p]);
            aw[p] += k;
        }
    }

    // ---- write partials (coalesced float4) ----
#pragma unroll
    for (int p = 0; p < PPT; ++p) {
        const int g = b * N_ + n0 + threadIdx.x + p * BLOCK;
        part[(size_t)sc * BN + g] = make_float4(ax[p], ay[p], az[p], aw[p]);
    }

    // ---- ticket: last finisher of this nb combines ----
    __threadfence();               // this thread's partial stores visible
    __syncthreads();               // all threads' fences done
    __shared__ int is_last;
    if (threadIdx.x == 0) {
        const int old = atomicAdd(&cnt[nb], 1);
        is_last = (old == SC - 1);
    }
    __syncthreads();
    if (!is_last) return;

    __threadfence();               // acquire: see all other blocks' partials
#pragma unroll
    for (int p = 0; p < PPT; ++p) {
        const int g = b * N_ + n0 + threadIdx.x + p * BLOCK;
        float4 s0v = make_float4(0.f, 0.f, 0.f, 0.f);
        float4 s1v = s0v, s2v = s0v, s3v = s0v;
#pragma unroll
        for (int c = 0; c < SC; c += 4) {
            const float4 p0 = part[(size_t)(c + 0) * BN + g];
            const float4 p1 = part[(size_t)(c + 1) * BN + g];
            const float4 p2 = part[(size_t)(c + 2) * BN + g];
            const float4 p3 = part[(size_t)(c + 3) * BN + g];
            s0v.x += p0.x; s0v.y += p0.y; s0v.z += p0.z; s0v.w += p0.w;
            s1v.x += p1.x; s1v.y += p1.y; s1v.z += p1.z; s1v.w += p1.w;
            s2v.x += p2.x; s2v.y += p2.y; s2v.z += p2.z; s2v.w += p2.w;
            s3v.x += p3.x; s3v.y += p3.y; s3v.z += p3.z; s3v.w += p3.w;
        }
        const float sx = (s0v.x + s1v.x) + (s2v.x + s3v.x);
        const float sy = (s0v.y + s1v.y) + (s2v.y + s3v.y);
        const float sz = (s0v.z + s1v.z) + (s2v.z + s3v.z);
        const float sw = (s0v.w + s1v.w) + (s2v.w + s3v.w);
        const float inv = 1.0f / sw;
        const int n = n0 + threadIdx.x + p * BLOCK;
        float* ob = out + b * 3 * N_;
        ob[n]          = sx * inv;
        ob[N_ + n]     = sy * inv;
        ob[2 * N_ + n] = sz * inv;
    }
}

// Fallback (ws too small): single kernel, full S staged in LDS, direct out.
__global__ __launch_bounds__(BLOCK, 1) void uf2_fused(
    const float* __restrict__ xyz,
    const float* __restrict__ sxyz,
    const float* __restrict__ sflow,
    const int* __restrict__ resol,
    float* __restrict__ out)
{
    constexpr int FPPT = 4;
    constexpr int PTS = BLOCK * FPPT;
    __shared__ float4 As[S_];
    __shared__ float4 Fs[S_];

    const int nb = blockIdx.x;
    const int b  = nb / (N_ / PTS);
    const int n0 = (nb % (N_ / PTS)) * PTS;

    const float r = (float)resol[0];
    const float inv_r2 = 1.0f / (r * r);
    const float c2 = 2.0f * inv_r2 * LOG2E;
    const float cy = -inv_r2 * LOG2E;

    const float* yb = sxyz  + b * 3 * S_;
    const float* fb = sflow + b * 3 * S_;
    for (int t = threadIdx.x; t < S_; t += BLOCK) {
        const float yx = yb[t], yy = yb[S_ + t], yz = yb[2 * S_ + t];
        const float fx = fb[t], fy = fb[S_ + t], fz = fb[2 * S_ + t];
        As[t] = make_float4(c2 * yx, c2 * yy, c2 * yz,
                            cy * (yx * yx + yy * yy + yz * yz));
        Fs[t] = make_float4(fx, fy, fz, 0.0f);
    }
    __syncthreads();

    const float* xb = xyz + b * 3 * N_;
    float px[FPPT], py[FPPT], pz[FPPT];
    float4 acc[FPPT];
#pragma unroll
    for (int p = 0; p < FPPT; ++p) {
        const int n = n0 + threadIdx.x + p * BLOCK;
        px[p] = xb[n]; py[p] = xb[N_ + n]; pz[p] = xb[2 * N_ + n];
        acc[p] = make_float4(0.f, 0.f, 0.f, 0.f);
    }
#pragma unroll 4
    for (int t = 0; t < S_; ++t) {
        const float4 a = As[t];
        const float4 f = Fs[t];
#pragma unroll
        for (int p = 0; p < FPPT; ++p) {
            float e = fmaf(pz[p], a.z, a.w);
            e = fmaf(py[p], a.y, e);
            e = fmaf(px[p], a.x, e);
            const float k = __builtin_amdgcn_exp2f(e);
            acc[p].x = fmaf(k, f.x, acc[p].x);
            acc[p].y = fmaf(k, f.y, acc[p].y);
            acc[p].z = fmaf(k, f.z, acc[p].z);
            acc[p].w += k;
        }
    }
#pragma unroll
    for (int p = 0; p < FPPT; ++p) {
        const int n = n0 + threadIdx.x + p * BLOCK;
        const float inv = 1.0f / acc[p].w;
        float* ob = out + b * 3 * N_;
        ob[n]          = acc[p].x * inv;
        ob[N_ + n]     = acc[p].y * inv;
        ob[2 * N_ + n] = acc[p].z * inv;
    }
}

extern "C" void kernel_launch(void* const* d_in, const int* in_sizes, int n_in,
                              void* d_out, int out_size, void* d_ws, size_t ws_size,
                              hipStream_t stream)
{
    const float* xyz   = (const float*)d_in[0];
    const float* sxyz  = (const float*)d_in[1];
    const float* sflow = (const float*)d_in[2];
    const int*   resol = (const int*)d_in[3];
    float* out = (float*)d_out;

    const size_t part_bytes = (size_t)SC * BN * sizeof(float4);   // 8 MB
    const size_t need = part_bytes + NB * sizeof(int);

    if (need > ws_size) {
        uf2_fused<<<dim3(BN / 1024), dim3(BLOCK), 0, stream>>>(
            xyz, sxyz, sflow, resol, out);
        return;
    }

    float4* part = (float4*)d_ws;
    int*    cnt  = (int*)((char*)d_ws + part_bytes);

    // zero the ticket counters (graph-legal async memset; reruns per replay)
    hipMemsetAsync(cnt, 0, NB * sizeof(int), stream);

    uf2_one<<<dim3(NB * SC), dim3(BLOCK), 0, stream>>>(
        xyz, sxyz, sflow, resol, part, cnt, out);
}